// Round 14
// baseline (148.433 us; speedup 1.0000x reference)
//
#include <hip/hip_runtime.h>
#include <hip/hip_bf16.h>

#define HID 512
#define OD  256
#define HP  513
#define EPSV 1e-5f

typedef float f32x16 __attribute__((ext_vector_type(16)));
typedef short s16x8  __attribute__((ext_vector_type(8)));

static __device__ __forceinline__ unsigned short f2bf(float f) {
    union { float f; unsigned u; } x; x.f = f;
    unsigned r = x.u + 0x7FFFu + ((x.u >> 16) & 1u);   // RNE
    return (unsigned short)(r >> 16);
}
static __device__ __forceinline__ unsigned pkbf(float x, float y) {
    float2 t; t.x = x; t.y = y;
    __hip_bfloat162 h = __float22bfloat162_rn(t);
    union { __hip_bfloat162 h; unsigned u; } c; c.h = h;
    return c.u;
}
static __device__ __forceinline__ float bfu(unsigned short u) {
    union { unsigned q; float f; } cv; cv.q = ((unsigned)u) << 16;
    return cv.f;
}

// permuted k-storage: within a 256-col half, storage s=(ll*8+c) holds true col
// j = c*32+ll. Applied identically to gpb/bpb/vhT -> MFMA pairing consistent.

// ---------- prep (fused): gpb/bpb, vhT, vh512, ahT, stats --------------------
__global__ void prep_all(const float* __restrict__ a, const float* __restrict__ v,
                         const float* __restrict__ gamma, const float* __restrict__ beta,
                         unsigned short* __restrict__ gpb, unsigned short* __restrict__ bpb,
                         unsigned short* __restrict__ vhT, float* __restrict__ vh512,
                         float* __restrict__ ahT, float* __restrict__ mu,
                         float* __restrict__ rsig) {
    __shared__ float s1[256], s2[256], s3[256], s4[256];
    int b = blockIdx.x, t = threadIdx.x;
    if (b < HP) {
        int ii = b;
        for (int s = t; s < 512; s += 256) {
            int half = s >> 8, ss = s & 255, ll = ss >> 3, c = ss & 7;
            int j = half * 256 + c * 32 + ll;
            gpb[(size_t)ii * 512 + s] = f2bf(gamma[(size_t)ii * HP + j]);
            bpb[(size_t)ii * 512 + s] = f2bf(beta [(size_t)ii * HP + j]);
        }
    } else if (b < HP + 128) {
        int m = b - HP;
        for (int s = t; s < 512; s += 256) {
            int half = s >> 8, ss = s & 255, ll = ss >> 3, c = ss & 7;
            int j = half * 256 + c * 32 + ll;
            float val = (j == 0) ? 1.f : v[m * HID + j - 1];
            vhT[(size_t)m * 512 + s] = f2bf(val);
        }
    } else if (b == HP + 128) {
        if (t < 128) vh512[t] = v[t * HID + 511];
    } else if (b < HP + 129 + 257) {
        int idx = (b - HP - 129) * 256 + t;
        if (idx < HP * 128) {
            int i = idx >> 7, m = idx & 127;
            ahT[idx] = (i == 0) ? 1.f : a[m * HID + i - 1];
        }
    } else {
        int m = b - (HP + 129 + 257);
        float a0 = a[m * HID + t], a1 = a[m * HID + t + 256];
        float v0 = v[m * HID + t], v1 = v[m * HID + t + 256];
        s1[t] = a0 + a1; s2[t] = a0 * a0 + a1 * a1;
        s3[t] = v0 + v1; s4[t] = v0 * v0 + v1 * v1;
        __syncthreads();
        for (int off = 128; off > 0; off >>= 1) {
            if (t < off) { s1[t] += s1[t + off]; s2[t] += s2[t + off];
                           s3[t] += s3[t + off]; s4[t] += s4[t + off]; }
            __syncthreads();
        }
        if (t == 0) {
            float Sa = 1.f + s1[0], Qa = 1.f + s2[0];
            float Sv = 1.f + s3[0], Qv = 1.f + s4[0];
            float muv = Sa * Sv / (float)((float)HP * (float)HP);
            float var = Qa * Qv / (float)((float)HP * (float)HP) - muv * muv;
            mu[m]   = muv;
            rsig[m] = rsqrtf(var + EPSV);
        }
    }
}

// ---------- stage: block o owns rows o*513+i, i<512; 32x32x16 MFMA -----------
// 16 groups x 2 halves; per half: CONV current (data issued 2 halves ago),
// THEN issue W/gamma for (g+1, same half) + beta for next half; lgkm-only
// barrier; 8 MFMA/wave. 2-half prefetch slack (~2400cy) at same registers.
__global__ __launch_bounds__(512, 2) void stage_fused(
        const float* __restrict__ W, const unsigned short* __restrict__ gpb,
        const unsigned short* __restrict__ bpb, const unsigned short* __restrict__ vhT,
        const float* __restrict__ ahT,
        float* __restrict__ Pout, float* __restrict__ Sgo, float* __restrict__ Sbo) {
    __shared__ __align__(16) char Bs[131072];      // [128 cols][1024B], swz (m&15)<<4
    __shared__ __align__(16) char bt[2][16384];    // A dbuf: [32 rows][512B], swz (r&15)<<4

    const int tid = threadIdx.x, lane = tid & 63, w = tid >> 6;
    const int l31 = lane & 31, kg = lane >> 5;
    const int cr = 2 * w + kg;                 // conv row 0..15 (pairs with cr+16)
    const int colm = (w & 3) * 32 + l31;       // wave's output col
    const int kslb = (w >> 2) * 8;             // wave's ksl range
    const int o = blockIdx.x;
    const unsigned rbase = (unsigned)o * 513u;

    // ---- fill B (swizzled), chunked ----------------------------------------
#pragma unroll
    for (int q0 = 0; q0 < 16; q0 += 4) {
        uint4 vals[4];
#pragma unroll
        for (int qq = 0; qq < 4; ++qq) {
            int idx = tid + (q0 + qq) * 512;
            int mr = idx >> 6, c = idx & 63;
            vals[qq] = *(const uint4*)(vhT + (size_t)mr * 512 + c * 8);
        }
#pragma unroll
        for (int qq = 0; qq < 4; ++qq) {
            int idx = tid + (q0 + qq) * 512;
            int mr = idx >> 6, c = idx & 63;
            *(uint4*)(&Bs[mr * 1024 + ((c * 16) ^ ((mr & 15) << 4))]) = vals[qq];
        }
    }

    float WrA[16], WrB[16];
    uint4 gaA1, gaA2, gaB1, gaB2;
    uint4 bbA1, bbA2, bbB1, bbB2;
    float ahv[16];
    f32x16 acc;
#pragma unroll
    for (int e = 0; e < 16; ++e) acc[e] = 0.f;
    float psum = 0.f, sg = 0.f, sb = 0.f;

    auto LOADW = [&](int g, int half, float (&dst)[16]) {
        const float* p1 = W + (size_t)(rbase + (unsigned)(g * 32 + cr)) * 513u + half * 256 + l31;
        const float* p2 = p1 + 16 * 513;
#pragma unroll
        for (int c = 0; c < 8; ++c) { dst[c] = p1[c * 32]; dst[8 + c] = p2[c * 32]; }
    };
    auto LOADG = [&](int g, int half, uint4& u1, uint4& u2) {
        u1 = *(const uint4*)(gpb + ((size_t)(g * 32 + cr) << 9) + half * 256 + l31 * 8);
        u2 = *(const uint4*)(gpb + ((size_t)(g * 32 + cr + 16) << 9) + half * 256 + l31 * 8);
    };
    auto LOADB = [&](int g, int half, uint4& u1, uint4& u2) {
        u1 = *(const uint4*)(bpb + ((size_t)(g * 32 + cr) << 9) + half * 256 + l31 * 8);
        u2 = *(const uint4*)(bpb + ((size_t)(g * 32 + cr + 16) << 9) + half * 256 + l31 * 8);
    };
    auto CONVROW = [&](const float* Wc, const uint4 gc, const uint4 b4, int row, char* tile) {
        const unsigned gw[4] = {gc.x, gc.y, gc.z, gc.w};
        const unsigned bw[4] = {b4.x, b4.y, b4.z, b4.w};
        float p[8];
        float s = 0.f, t2 = 0.f;
#pragma unroll
        for (int e = 0; e < 8; ++e) {
            unsigned ug = (e & 1) ? (gw[e >> 1] >> 16) : (gw[e >> 1] & 0xffffu);
            unsigned ub = (e & 1) ? (bw[e >> 1] >> 16) : (bw[e >> 1] & 0xffffu);
            p[e] = bfu((unsigned short)ug) * Wc[e];
            s += p[e];
            t2 = fmaf(bfu((unsigned short)ub), Wc[e], t2);
        }
        uint4 o4;
        o4.x = pkbf(p[0], p[1]); o4.y = pkbf(p[2], p[3]);
        o4.z = pkbf(p[4], p[5]); o4.w = pkbf(p[6], p[7]);
        *(uint4*)(tile + row * 512 + ((l31 * 16) ^ ((row & 15) << 4))) = o4;
        sg += s; sb += t2;
    };

    // prologue: bodies (0,h0) and (0,h1) for W/gamma; beta for (0,h0)
    LOADW(0, 0, WrA); LOADG(0, 0, gaA1, gaA2);
    LOADW(0, 1, WrB); LOADG(0, 1, gaB1, gaB2);
    LOADB(0, 0, bbA1, bbA2);
    __syncthreads();   // B-fill visible (one-time vmcnt drain)

#pragma unroll 1
    for (int g = 0; g < 16; ++g) {
        // ================= half 0 =================
        CONVROW(&WrA[0], gaA1, bbA1, cr,      bt[0]);
        CONVROW(&WrA[8], gaA2, bbA2, cr + 16, bt[0]);
        if (g < 15) { LOADW(g + 1, 0, WrA); LOADG(g + 1, 0, gaA1, gaA2); }
        LOADB(g, 1, bbB1, bbB2);               // beta for half1 (1-half slack)
#pragma unroll
        for (int e = 0; e < 16; ++e) {
            int row32 = (e & 3) + 8 * (e >> 2) + 4 * kg;
            ahv[e] = ahT[(size_t)(g * 32 + row32) * 128 + colm];
        }

        __builtin_amdgcn_sched_barrier(0);
        asm volatile("s_waitcnt lgkmcnt(0)" ::: "memory");
        __builtin_amdgcn_s_barrier();
        __builtin_amdgcn_sched_barrier(0);

#pragma unroll
        for (int i2 = 0; i2 < 8; ++i2) {
            int ksl = kslb + i2;
            s16x8 afr = *(const s16x8*)(&bt[0][l31 * 512 +
                          ((ksl * 32 + kg * 16) ^ ((l31 & 15) << 4))]);
            s16x8 bfr = *(const s16x8*)(&Bs[colm * 1024 +
                          ((ksl * 32 + kg * 16) ^ ((colm & 15) << 4))]);
            acc = __builtin_amdgcn_mfma_f32_32x32x16_bf16(afr, bfr, acc, 0, 0, 0);
        }

        // ================= half 1 =================
        CONVROW(&WrB[0], gaB1, bbB1, cr,      bt[1]);
        CONVROW(&WrB[8], gaB2, bbB2, cr + 16, bt[1]);
        if (g < 15) {
            LOADW(g + 1, 1, WrB); LOADG(g + 1, 1, gaB1, gaB2);
            LOADB(g + 1, 0, bbA1, bbA2);       // beta for next half0
        }

        __builtin_amdgcn_sched_barrier(0);
        asm volatile("s_waitcnt lgkmcnt(0)" ::: "memory");
        __builtin_amdgcn_s_barrier();
        __builtin_amdgcn_sched_barrier(0);

#pragma unroll
        for (int i2 = 0; i2 < 8; ++i2) {
            int ksl = kslb + i2;
            s16x8 afr = *(const s16x8*)(&bt[1][l31 * 512 +
                          ((ksl * 32 + kg * 16) ^ ((l31 & 15) << 4))]);
            s16x8 bfr = *(const s16x8*)(&Bs[colm * 1024 +
                          ((512 + ksl * 32 + kg * 16) ^ ((colm & 15) << 4))]);
            acc = __builtin_amdgcn_mfma_f32_32x32x16_bf16(afr, bfr, acc, 0, 0, 0);
        }
        // fold this group (C/D: col=lane&31, row=(e&3)+8*(e>>2)+4*(lane>>5))
#pragma unroll
        for (int e = 0; e < 16; ++e) psum = fmaf(acc[e], ahv[e], psum);
#pragma unroll
        for (int e = 0; e < 16; ++e) acc[e] = 0.f;
    }

    // ---- epilogue (reuse Bs as scratch after all reads done) ---------------
    __syncthreads();
    float* redP  = (float*)Bs;          // [128 cols][2 wave-pairs]
    float* redSg = redP + 256;
    float* redSb = redP + 264;
    psum += __shfl_xor(psum, 32);
#pragma unroll
    for (int off = 1; off < 64; off <<= 1) {
        sg += __shfl_xor(sg, off); sb += __shfl_xor(sb, off);
    }
    if (lane < 32) redP[colm * 2 + (w >> 2)] = psum;
    if (lane == 0) { redSg[w] = sg; redSb[w] = sb; }
    __syncthreads();
    if (tid < 128) Pout[(size_t)o * 128 + tid] = redP[tid * 2] + redP[tid * 2 + 1];
    if (tid == 0) {
        float S = 0.f, T = 0.f;
#pragma unroll
        for (int k = 0; k < 8; ++k) { S += redSg[k]; T += redSb[k]; }
        Sgo[o] = S; Sbo[o] = T;
    }
}

// ---------- finalize: i=512 / j=512 peels inline + LN fold + bias + relu -----
__global__ void finalize_kernel(const float* __restrict__ Pout, const float* __restrict__ Sgo,
                                const float* __restrict__ Sbo, const float* __restrict__ ahT,
                                const float* __restrict__ vh512, const unsigned short* __restrict__ vhT,
                                const float* __restrict__ W, const float* __restrict__ gamma,
                                const float* __restrict__ beta, const float* __restrict__ mu,
                                const float* __restrict__ rsig, const float* __restrict__ bias,
                                float* __restrict__ out) {
    __shared__ float wg[HP], wb[HP], gws[512], bws[512];
    __shared__ float redP[2][128], redD[2][128], redS[4];
    int o = blockIdx.x, tid = threadIdx.x;     // 256 threads
    int m = tid & 127, h = tid >> 7;
    for (int i = tid; i < HP; i += 256) {      // col j=512 of slice i (gamma/beta scaled)
        float wv = W[((size_t)((unsigned)o * 513u + (unsigned)i)) * 513u + 512u];
        wg[i] = gamma[(size_t)i * HP + 512] * wv;
        wb[i] = beta [(size_t)i * HP + 512] * wv;
    }
    for (int j = tid; j < 512; j += 256) {     // row i=512, j<512 (permuted slots)
        float wv = W[((size_t)((unsigned)o * 513u + 512u)) * 513u + j];
        int s = ((j >> 8) << 8) + ((j & 31) << 3) + ((j & 255) >> 5);
        gws[s] = gamma[(size_t)512 * HP + j] * wv;
        bws[s] = beta [(size_t)512 * HP + j] * wv;
    }
    __syncthreads();
    int i0 = h ? 257 : 0, i1 = h ? 513 : 257;
    float Pf = 0.f, Sgf = 0.f, Sbf = 0.f;
    for (int i = i0; i < i1; ++i) {
        float g = wg[i];
        Pf = fmaf(ahT[(size_t)i * 128 + m], g, Pf);
        Sgf += g; Sbf += wb[i];
    }
    int s0 = h * 256, s1 = s0 + 256;
    float dot = 0.f;
    const unsigned short* vr = vhT + (size_t)m * 512;
    for (int s = s0; s < s1; ++s) {
        float g = gws[s];
        dot = fmaf(bfu(vr[s]), g, dot);
        Sgf += g; Sbf += bws[s];
    }
    redP[h][m] = Pf; redD[h][m] = dot;
    if (m == 0) { redS[h * 2] = Sgf; redS[h * 2 + 1] = Sbf; }
    __syncthreads();
    if (h == 0) {
        float P = Pout[(size_t)o * 128 + m]
                + vh512[m] * (redP[0][m] + redP[1][m])
                + ahT[(size_t)512 * 128 + m] * (redD[0][m] + redD[1][m]);
        float Sg = Sgo[o] + redS[0] + redS[2];
        float Sb = Sbo[o] + redS[1] + redS[3];
        float x = rsig[m] * (P - mu[m] * Sg) + Sb + bias[o];
        out[m * OD + o] = fmaxf(x, 0.f);
    }
}

extern "C" void kernel_launch(void* const* d_in, const int* in_sizes, int n_in,
                              void* d_out, int out_size, void* d_ws, size_t ws_size,
                              hipStream_t stream) {
    const float* a     = (const float*)d_in[0];
    const float* v     = (const float*)d_in[1];
    const float* gamma = (const float*)d_in[2];
    const float* beta  = (const float*)d_in[3];
    const float* W     = (const float*)d_in[4];
    const float* bias  = (const float*)d_in[5];
    float* out = (float*)d_out;

    float* cur = (float*)d_ws;
    float* mu    = cur; cur += 128;
    float* rsig  = cur; cur += 128;
    float* Sgo   = cur; cur += 256;
    float* Sbo   = cur; cur += 256;
    float* Pout  = cur; cur += (size_t)OD * 128;        // 32768
    float* ahT   = cur; cur += (size_t)HP * 128;        // 65664
    float* vh512 = cur; cur += 128;
    unsigned short* gpb = (unsigned short*)cur;          // 513*512
    unsigned short* bpb = gpb + (size_t)HP * 512;
    unsigned short* vhT = bpb + (size_t)HP * 512;        // 128*512

    prep_all<<<HP + 129 + 257 + 128, 256, 0, stream>>>(a, v, gamma, beta, gpb, bpb,
                                                       vhT, vh512, ahT, mu, rsig);
    stage_fused<<<OD, 512, 0, stream>>>(W, gpb, bpb, vhT, ahT, Pout, Sgo, Sbo);
    finalize_kernel<<<OD, 256, 0, stream>>>(Pout, Sgo, Sbo, ahT, vh512, vhT,
                                            W, gamma, beta, mu, rsig, bias, out);
}

// Round 15
// 137.025 us; speedup vs baseline: 1.0833x; 1.0833x over previous
//
#include <hip/hip_runtime.h>
#include <hip/hip_bf16.h>

#define HID 512
#define OD  256
#define HP  513
#define EPSV 1e-5f

typedef float f32x16 __attribute__((ext_vector_type(16)));
typedef short s16x8  __attribute__((ext_vector_type(8)));

static __device__ __forceinline__ unsigned short f2bf(float f) {
    union { float f; unsigned u; } x; x.f = f;
    unsigned r = x.u + 0x7FFFu + ((x.u >> 16) & 1u);   // RNE
    return (unsigned short)(r >> 16);
}
static __device__ __forceinline__ unsigned pkbf(float x, float y) {
    float2 t; t.x = x; t.y = y;
    __hip_bfloat162 h = __float22bfloat162_rn(t);
    union { __hip_bfloat162 h; unsigned u; } c; c.h = h;
    return c.u;
}
static __device__ __forceinline__ float bfu(unsigned short u) {
    union { unsigned q; float f; } cv; cv.q = ((unsigned)u) << 16;
    return cv.f;
}

// permuted k-storage: within a 256-col half, storage s=(ll*8+c) holds true col
// j = c*32+ll. Applied identically to gpb/bpb/vhT -> MFMA pairing consistent.

// ---------- prep (fused): gpb/bpb, vhT, vh512, ahT, stats --------------------
__global__ void prep_all(const float* __restrict__ a, const float* __restrict__ v,
                         const float* __restrict__ gamma, const float* __restrict__ beta,
                         unsigned short* __restrict__ gpb, unsigned short* __restrict__ bpb,
                         unsigned short* __restrict__ vhT, float* __restrict__ vh512,
                         float* __restrict__ ahT, float* __restrict__ mu,
                         float* __restrict__ rsig) {
    __shared__ float s1[256], s2[256], s3[256], s4[256];
    int b = blockIdx.x, t = threadIdx.x;
    if (b < HP) {
        int ii = b;
        for (int s = t; s < 512; s += 256) {
            int half = s >> 8, ss = s & 255, ll = ss >> 3, c = ss & 7;
            int j = half * 256 + c * 32 + ll;
            gpb[(size_t)ii * 512 + s] = f2bf(gamma[(size_t)ii * HP + j]);
            bpb[(size_t)ii * 512 + s] = f2bf(beta [(size_t)ii * HP + j]);
        }
    } else if (b < HP + 128) {
        int m = b - HP;
        for (int s = t; s < 512; s += 256) {
            int half = s >> 8, ss = s & 255, ll = ss >> 3, c = ss & 7;
            int j = half * 256 + c * 32 + ll;
            float val = (j == 0) ? 1.f : v[m * HID + j - 1];
            vhT[(size_t)m * 512 + s] = f2bf(val);
        }
    } else if (b == HP + 128) {
        if (t < 128) vh512[t] = v[t * HID + 511];
    } else if (b < HP + 129 + 257) {
        int idx = (b - HP - 129) * 256 + t;
        if (idx < HP * 128) {
            int i = idx >> 7, m = idx & 127;
            ahT[idx] = (i == 0) ? 1.f : a[m * HID + i - 1];
        }
    } else {
        int m = b - (HP + 129 + 257);
        float a0 = a[m * HID + t], a1 = a[m * HID + t + 256];
        float v0 = v[m * HID + t], v1 = v[m * HID + t + 256];
        s1[t] = a0 + a1; s2[t] = a0 * a0 + a1 * a1;
        s3[t] = v0 + v1; s4[t] = v0 * v0 + v1 * v1;
        __syncthreads();
        for (int off = 128; off > 0; off >>= 1) {
            if (t < off) { s1[t] += s1[t + off]; s2[t] += s2[t + off];
                           s3[t] += s3[t + off]; s4[t] += s4[t + off]; }
            __syncthreads();
        }
        if (t == 0) {
            float Sa = 1.f + s1[0], Qa = 1.f + s2[0];
            float Sv = 1.f + s3[0], Qv = 1.f + s4[0];
            float muv = Sa * Sv / (float)((float)HP * (float)HP);
            float var = Qa * Qv / (float)((float)HP * (float)HP) - muv * muv;
            mu[m]   = muv;
            rsig[m] = rsqrtf(var + EPSV);
        }
    }
}

// ---------- stage: block o owns rows o*513+i, i<512; 32x32x16 MFMA -----------
// EXACT R13 structure (measured fastest): per half, beta loaded in-body first,
// then W/gamma prefetch for next half, CONV, lgkm-only barrier, 8 MFMA/wave.
__global__ __launch_bounds__(512, 2) void stage_fused(
        const float* __restrict__ W, const unsigned short* __restrict__ gpb,
        const unsigned short* __restrict__ bpb, const unsigned short* __restrict__ vhT,
        const float* __restrict__ ahT,
        float* __restrict__ Pout, float* __restrict__ Sgo, float* __restrict__ Sbo) {
    __shared__ __align__(16) char Bs[131072];      // [128 cols][1024B], swz (m&15)<<4
    __shared__ __align__(16) char bt[2][16384];    // A dbuf: [32 rows][512B], swz (r&15)<<4

    const int tid = threadIdx.x, lane = tid & 63, w = tid >> 6;
    const int l31 = lane & 31, kg = lane >> 5;
    const int cr = 2 * w + kg;                 // conv row 0..15 (pairs with cr+16)
    const int colm = (w & 3) * 32 + l31;       // wave's output col
    const int kslb = (w >> 2) * 8;             // wave's ksl range
    const int o = blockIdx.x;
    const unsigned rbase = (unsigned)o * 513u;

    // ---- fill B (swizzled), chunked ----------------------------------------
#pragma unroll
    for (int q0 = 0; q0 < 16; q0 += 4) {
        uint4 vals[4];
#pragma unroll
        for (int qq = 0; qq < 4; ++qq) {
            int idx = tid + (q0 + qq) * 512;
            int mr = idx >> 6, c = idx & 63;
            vals[qq] = *(const uint4*)(vhT + (size_t)mr * 512 + c * 8);
        }
#pragma unroll
        for (int qq = 0; qq < 4; ++qq) {
            int idx = tid + (q0 + qq) * 512;
            int mr = idx >> 6, c = idx & 63;
            *(uint4*)(&Bs[mr * 1024 + ((c * 16) ^ ((mr & 15) << 4))]) = vals[qq];
        }
    }

    float WrA[16], WrB[16];
    uint4 gaA1, gaA2, gaB1, gaB2;
    float ahv[16];
    f32x16 acc;
#pragma unroll
    for (int e = 0; e < 16; ++e) acc[e] = 0.f;
    float psum = 0.f, sg = 0.f, sb = 0.f;

    auto LOADW = [&](int g, int half, float (&dst)[16]) {
        const float* p1 = W + (size_t)(rbase + (unsigned)(g * 32 + cr)) * 513u + half * 256 + l31;
        const float* p2 = p1 + 16 * 513;
#pragma unroll
        for (int c = 0; c < 8; ++c) { dst[c] = p1[c * 32]; dst[8 + c] = p2[c * 32]; }
    };
    auto LOADG = [&](int g, int half, uint4& u1, uint4& u2) {
        u1 = *(const uint4*)(gpb + ((size_t)(g * 32 + cr) << 9) + half * 256 + l31 * 8);
        u2 = *(const uint4*)(gpb + ((size_t)(g * 32 + cr + 16) << 9) + half * 256 + l31 * 8);
    };
    auto CONVROW = [&](const float* Wc, const uint4 gc, const uint4 b4, int row, char* tile) {
        const unsigned gw[4] = {gc.x, gc.y, gc.z, gc.w};
        const unsigned bw[4] = {b4.x, b4.y, b4.z, b4.w};
        float p[8];
        float s = 0.f, t2 = 0.f;
#pragma unroll
        for (int e = 0; e < 8; ++e) {
            unsigned ug = (e & 1) ? (gw[e >> 1] >> 16) : (gw[e >> 1] & 0xffffu);
            unsigned ub = (e & 1) ? (bw[e >> 1] >> 16) : (bw[e >> 1] & 0xffffu);
            p[e] = bfu((unsigned short)ug) * Wc[e];
            s += p[e];
            t2 = fmaf(bfu((unsigned short)ub), Wc[e], t2);
        }
        uint4 o4;
        o4.x = pkbf(p[0], p[1]); o4.y = pkbf(p[2], p[3]);
        o4.z = pkbf(p[4], p[5]); o4.w = pkbf(p[6], p[7]);
        *(uint4*)(tile + row * 512 + ((l31 * 16) ^ ((row & 15) << 4))) = o4;
        sg += s; sb += t2;
    };

    // prologue
    LOADW(0, 0, WrA); LOADG(0, 0, gaA1, gaA2);
    __syncthreads();   // B-fill visible (one-time vmcnt drain)

#pragma unroll 1
    for (int g = 0; g < 16; ++g) {
        // ================= half 0 =================
        uint4 bb1 = *(const uint4*)(bpb + ((size_t)(g * 32 + cr) << 9) + l31 * 8);
        uint4 bb2 = *(const uint4*)(bpb + ((size_t)(g * 32 + cr + 16) << 9) + l31 * 8);
        LOADW(g, 1, WrB); LOADG(g, 1, gaB1, gaB2);
        CONVROW(&WrA[0], gaA1, bb1, cr,      bt[0]);
        CONVROW(&WrA[8], gaA2, bb2, cr + 16, bt[0]);

        __builtin_amdgcn_sched_barrier(0);
        asm volatile("s_waitcnt lgkmcnt(0)" ::: "memory");
        __builtin_amdgcn_s_barrier();
        __builtin_amdgcn_sched_barrier(0);

#pragma unroll
        for (int i2 = 0; i2 < 8; ++i2) {
            int ksl = kslb + i2;
            s16x8 afr = *(const s16x8*)(&bt[0][l31 * 512 +
                          ((ksl * 32 + kg * 16) ^ ((l31 & 15) << 4))]);
            s16x8 bfr = *(const s16x8*)(&Bs[colm * 1024 +
                          ((ksl * 32 + kg * 16) ^ ((colm & 15) << 4))]);
            acc = __builtin_amdgcn_mfma_f32_32x32x16_bf16(afr, bfr, acc, 0, 0, 0);
        }

        // ================= half 1 =================
        uint4 cb1 = *(const uint4*)(bpb + ((size_t)(g * 32 + cr) << 9) + 256 + l31 * 8);
        uint4 cb2 = *(const uint4*)(bpb + ((size_t)(g * 32 + cr + 16) << 9) + 256 + l31 * 8);
        if (g < 15) { LOADW(g + 1, 0, WrA); LOADG(g + 1, 0, gaA1, gaA2); }
#pragma unroll
        for (int e = 0; e < 16; ++e) {
            int row32 = (e & 3) + 8 * (e >> 2) + 4 * kg;
            ahv[e] = ahT[(size_t)(g * 32 + row32) * 128 + colm];
        }
        CONVROW(&WrB[0], gaB1, cb1, cr,      bt[1]);
        CONVROW(&WrB[8], gaB2, cb2, cr + 16, bt[1]);

        __builtin_amdgcn_sched_barrier(0);
        asm volatile("s_waitcnt lgkmcnt(0)" ::: "memory");
        __builtin_amdgcn_s_barrier();
        __builtin_amdgcn_sched_barrier(0);

#pragma unroll
        for (int i2 = 0; i2 < 8; ++i2) {
            int ksl = kslb + i2;
            s16x8 afr = *(const s16x8*)(&bt[1][l31 * 512 +
                          ((ksl * 32 + kg * 16) ^ ((l31 & 15) << 4))]);
            s16x8 bfr = *(const s16x8*)(&Bs[colm * 1024 +
                          ((512 + ksl * 32 + kg * 16) ^ ((colm & 15) << 4))]);
            acc = __builtin_amdgcn_mfma_f32_32x32x16_bf16(afr, bfr, acc, 0, 0, 0);
        }
        // fold this group (C/D: col=lane&31, row=(e&3)+8*(e>>2)+4*(lane>>5))
#pragma unroll
        for (int e = 0; e < 16; ++e) psum = fmaf(acc[e], ahv[e], psum);
#pragma unroll
        for (int e = 0; e < 16; ++e) acc[e] = 0.f;
    }

    // ---- epilogue (reuse Bs as scratch after all reads done) ---------------
    __syncthreads();
    float* redP  = (float*)Bs;          // [128 cols][2 wave-pairs]
    float* redSg = redP + 256;
    float* redSb = redP + 264;
    psum += __shfl_xor(psum, 32);
#pragma unroll
    for (int off = 1; off < 64; off <<= 1) {
        sg += __shfl_xor(sg, off); sb += __shfl_xor(sb, off);
    }
    if (lane < 32) redP[colm * 2 + (w >> 2)] = psum;
    if (lane == 0) { redSg[w] = sg; redSb[w] = sb; }
    __syncthreads();
    if (tid < 128) Pout[(size_t)o * 128 + tid] = redP[tid * 2] + redP[tid * 2 + 1];
    if (tid == 0) {
        float S = 0.f, T = 0.f;
#pragma unroll
        for (int k = 0; k < 8; ++k) { S += redSg[k]; T += redSb[k]; }
        Sgo[o] = S; Sbo[o] = T;
    }
}

// ---------- finalize: i=512 / j=512 peels inline + LN fold + bias + relu -----
__global__ void finalize_kernel(const float* __restrict__ Pout, const float* __restrict__ Sgo,
                                const float* __restrict__ Sbo, const float* __restrict__ ahT,
                                const float* __restrict__ vh512, const unsigned short* __restrict__ vhT,
                                const float* __restrict__ W, const float* __restrict__ gamma,
                                const float* __restrict__ beta, const float* __restrict__ mu,
                                const float* __restrict__ rsig, const float* __restrict__ bias,
                                float* __restrict__ out) {
    __shared__ float wg[HP], wb[HP], gws[512], bws[512];
    __shared__ float redP[2][128], redD[2][128], redS[4];
    int o = blockIdx.x, tid = threadIdx.x;     // 256 threads
    int m = tid & 127, h = tid >> 7;
    for (int i = tid; i < HP; i += 256) {      // col j=512 of slice i (gamma/beta scaled)
        float wv = W[((size_t)((unsigned)o * 513u + (unsigned)i)) * 513u + 512u];
        wg[i] = gamma[(size_t)i * HP + 512] * wv;
        wb[i] = beta [(size_t)i * HP + 512] * wv;
    }
    for (int j = tid; j < 512; j += 256) {     // row i=512, j<512 (permuted slots)
        float wv = W[((size_t)((unsigned)o * 513u + 512u)) * 513u + j];
        int s = ((j >> 8) << 8) + ((j & 31) << 3) + ((j & 255) >> 5);
        gws[s] = gamma[(size_t)512 * HP + j] * wv;
        bws[s] = beta [(size_t)512 * HP + j] * wv;
    }
    __syncthreads();
    int i0 = h ? 257 : 0, i1 = h ? 513 : 257;
    float Pf = 0.f, Sgf = 0.f, Sbf = 0.f;
    for (int i = i0; i < i1; ++i) {
        float g = wg[i];
        Pf = fmaf(ahT[(size_t)i * 128 + m], g, Pf);
        Sgf += g; Sbf += wb[i];
    }
    int s0 = h * 256, s1 = s0 + 256;
    float dot = 0.f;
    const unsigned short* vr = vhT + (size_t)m * 512;
    for (int s = s0; s < s1; ++s) {
        float g = gws[s];
        dot = fmaf(bfu(vr[s]), g, dot);
        Sgf += g; Sbf += bws[s];
    }
    redP[h][m] = Pf; redD[h][m] = dot;
    if (m == 0) { redS[h * 2] = Sgf; redS[h * 2 + 1] = Sbf; }
    __syncthreads();
    if (h == 0) {
        float P = Pout[(size_t)o * 128 + m]
                + vh512[m] * (redP[0][m] + redP[1][m])
                + ahT[(size_t)512 * 128 + m] * (redD[0][m] + redD[1][m]);
        float Sg = Sgo[o] + redS[0] + redS[2];
        float Sb = Sbo[o] + redS[1] + redS[3];
        float x = rsig[m] * (P - mu[m] * Sg) + Sb + bias[o];
        out[m * OD + o] = fmaxf(x, 0.f);
    }
}

extern "C" void kernel_launch(void* const* d_in, const int* in_sizes, int n_in,
                              void* d_out, int out_size, void* d_ws, size_t ws_size,
                              hipStream_t stream) {
    const float* a     = (const float*)d_in[0];
    const float* v     = (const float*)d_in[1];
    const float* gamma = (const float*)d_in[2];
    const float* beta  = (const float*)d_in[3];
    const float* W     = (const float*)d_in[4];
    const float* bias  = (const float*)d_in[5];
    float* out = (float*)d_out;

    float* cur = (float*)d_ws;
    float* mu    = cur; cur += 128;
    float* rsig  = cur; cur += 128;
    float* Sgo   = cur; cur += 256;
    float* Sbo   = cur; cur += 256;
    float* Pout  = cur; cur += (size_t)OD * 128;        // 32768
    float* ahT   = cur; cur += (size_t)HP * 128;        // 65664
    float* vh512 = cur; cur += 128;
    unsigned short* gpb = (unsigned short*)cur;          // 513*512
    unsigned short* bpb = gpb + (size_t)HP * 512;
    unsigned short* vhT = bpb + (size_t)HP * 512;        // 128*512

    prep_all<<<HP + 129 + 257 + 128, 256, 0, stream>>>(a, v, gamma, beta, gpb, bpb,
                                                       vhT, vh512, ahT, mu, rsig);
    stage_fused<<<OD, 512, 0, stream>>>(W, gpb, bpb, vhT, ahT, Pout, Sgo, Sbo);
    finalize_kernel<<<OD, 256, 0, stream>>>(Pout, Sgo, Sbo, ahT, vh512, vhT,
                                            W, gamma, beta, mu, rsig, bias, out);
}

// Round 17
// 105.799 us; speedup vs baseline: 1.4030x; 1.2951x over previous
//
#include <hip/hip_runtime.h>
#include <hip/hip_bf16.h>

#define HID 512
#define OD  256
#define HP  513
#define EPSV 1e-5f

typedef float f32x16 __attribute__((ext_vector_type(16)));
typedef short s16x8  __attribute__((ext_vector_type(8)));

static __device__ __forceinline__ unsigned short f2bf(float f) {
    union { float f; unsigned u; } x; x.f = f;
    unsigned r = x.u + 0x7FFFu + ((x.u >> 16) & 1u);   // RNE
    return (unsigned short)(r >> 16);
}
static __device__ __forceinline__ unsigned pkbf(float x, float y) {
    float2 t; t.x = x; t.y = y;
    __hip_bfloat162 h = __float22bfloat162_rn(t);
    union { __hip_bfloat162 h; unsigned u; } c; c.h = h;
    return c.u;
}
static __device__ __forceinline__ float bfu(unsigned short u) {
    union { unsigned q; float f; } cv; cv.q = ((unsigned)u) << 16;
    return cv.f;
}

// permuted k-storage: within a 256-col half, storage s=(ll*8+c) holds true col
// j = c*32+ll. Applied identically to gpb/bpb/vhT -> MFMA pairing consistent.

// ---------- prep: gpb/bpb (bf16, permuted), vhT (bf16, permuted), vh512, ahT -
__global__ void prep_all(const float* __restrict__ a, const float* __restrict__ v,
                         const float* __restrict__ gamma, const float* __restrict__ beta,
                         unsigned short* __restrict__ gpb, unsigned short* __restrict__ bpb,
                         unsigned short* __restrict__ vhT, float* __restrict__ vh512,
                         float* __restrict__ ahT) {
    int b = blockIdx.x, t = threadIdx.x;
    if (b < HP) {
        int ii = b;
        for (int s = t; s < 512; s += 256) {
            int half = s >> 8, ss = s & 255, ll = ss >> 3, c = ss & 7;
            int j = half * 256 + c * 32 + ll;
            gpb[(size_t)ii * 512 + s] = f2bf(gamma[(size_t)ii * HP + j]);
            bpb[(size_t)ii * 512 + s] = f2bf(beta [(size_t)ii * HP + j]);
        }
    } else if (b < HP + 128) {
        int m = b - HP;
        for (int s = t; s < 512; s += 256) {
            int half = s >> 8, ss = s & 255, ll = ss >> 3, c = ss & 7;
            int j = half * 256 + c * 32 + ll;
            float val = (j == 0) ? 1.f : v[m * HID + j - 1];
            vhT[(size_t)m * 512 + s] = f2bf(val);
        }
    } else if (b == HP + 128) {
        if (t < 128) vh512[t] = v[t * HID + 511];
    } else {
        int idx = (b - HP - 129) * 256 + t;
        if (idx < HP * 128) {
            int i = idx >> 7, m = idx & 127;
            ahT[idx] = (i == 0) ? 1.f : a[m * HID + i - 1];
        }
    }
}

// ---------- prep2: gather col-512 of W, pre-scaled by gamma/beta -------------
__global__ void prep_w5(const float* __restrict__ W, const float* __restrict__ gamma,
                        const float* __restrict__ beta,
                        float* __restrict__ w5g, float* __restrict__ w5b) {
    int oi = blockIdx.x * 256 + threadIdx.x;
    if (oi < OD * HP) {
        unsigned ii = (unsigned)oi % 513u;
        float wv = W[(size_t)oi * 513u + 512u];
        w5g[oi] = gamma[(size_t)ii * HP + 512] * wv;
        w5b[oi] = beta [(size_t)ii * HP + 512] * wv;
    }
}

// ---------- stats ------------------------------------------------------------
__global__ void stats_kernel(const float* __restrict__ a, const float* __restrict__ v,
                             float* __restrict__ mu, float* __restrict__ rsig) {
    __shared__ float s1[256], s2[256], s3[256], s4[256];
    int m = blockIdx.x, t = threadIdx.x;
    float a0 = a[m * HID + t], a1 = a[m * HID + t + 256];
    float v0 = v[m * HID + t], v1 = v[m * HID + t + 256];
    s1[t] = a0 + a1; s2[t] = a0 * a0 + a1 * a1;
    s3[t] = v0 + v1; s4[t] = v0 * v0 + v1 * v1;
    __syncthreads();
    for (int off = 128; off > 0; off >>= 1) {
        if (t < off) { s1[t] += s1[t + off]; s2[t] += s2[t + off];
                       s3[t] += s3[t + off]; s4[t] += s4[t + off]; }
        __syncthreads();
    }
    if (t == 0) {
        float Sa = 1.f + s1[0], Qa = 1.f + s2[0];
        float Sv = 1.f + s3[0], Qv = 1.f + s4[0];
        float muv = Sa * Sv / (float)((float)HP * (float)HP);
        float var = Qa * Qv / (float)((float)HP * (float)HP) - muv * muv;
        mu[m]   = muv;
        rsig[m] = rsqrtf(var + EPSV);
    }
}

// ---------- stage: block o owns rows o*513+i, i<512; 32x32x16 MFMA -----------
// 16 groups x 32 rows; per body (group, k-half): conv 2 rows/thread -> A-tile
// (swizzled dbuf), lgkmcnt-only barrier, 8 MFMA/wave (waves: 4 col-chunks x
// 2 ksl-halves). Rolled loop, named prefetch sets. Row i=512 -> finalize.
__global__ __launch_bounds__(512, 2) void stage_fused(
        const float* __restrict__ W, const unsigned short* __restrict__ gpb,
        const unsigned short* __restrict__ bpb, const unsigned short* __restrict__ vhT,
        const float* __restrict__ ahT,
        float* __restrict__ Pout, float* __restrict__ Sgo, float* __restrict__ Sbo) {
    __shared__ __align__(16) char Bs[131072];      // [128 cols][1024B], swz (m&15)<<4
    __shared__ __align__(16) char bt[2][16384];    // A dbuf: [32 rows][512B], swz (r&15)<<4

    const int tid = threadIdx.x, lane = tid & 63, w = tid >> 6;
    const int l31 = lane & 31, kg = lane >> 5;
    const int cr = 2 * w + kg;                 // conv row 0..15 (pairs with cr+16)
    const int colm = (w & 3) * 32 + l31;       // wave's output col
    const int kslb = (w >> 2) * 8;             // wave's ksl range
    const int o = blockIdx.x;
    const unsigned rbase = (unsigned)o * 513u;

    // ---- fill B (swizzled), chunked ----------------------------------------
#pragma unroll
    for (int q0 = 0; q0 < 16; q0 += 4) {
        uint4 vals[4];
#pragma unroll
        for (int qq = 0; qq < 4; ++qq) {
            int idx = tid + (q0 + qq) * 512;
            int mr = idx >> 6, c = idx & 63;
            vals[qq] = *(const uint4*)(vhT + (size_t)mr * 512 + c * 8);
        }
#pragma unroll
        for (int qq = 0; qq < 4; ++qq) {
            int idx = tid + (q0 + qq) * 512;
            int mr = idx >> 6, c = idx & 63;
            *(uint4*)(&Bs[mr * 1024 + ((c * 16) ^ ((mr & 15) << 4))]) = vals[qq];
        }
    }

    float WrA[16], WrB[16];
    uint4 gaA1, gaA2, gaB1, gaB2;
    float ahv[16];
    f32x16 acc;
#pragma unroll
    for (int e = 0; e < 16; ++e) acc[e] = 0.f;
    float psum = 0.f, sg = 0.f, sb = 0.f;

    auto LOADW = [&](int g, int half, float (&dst)[16]) {
        const float* p1 = W + (size_t)(rbase + (unsigned)(g * 32 + cr)) * 513u + half * 256 + l31;
        const float* p2 = p1 + 16 * 513;
#pragma unroll
        for (int c = 0; c < 8; ++c) { dst[c] = p1[c * 32]; dst[8 + c] = p2[c * 32]; }
    };
    auto LOADG = [&](int g, int half, uint4& u1, uint4& u2) {
        u1 = *(const uint4*)(gpb + ((size_t)(g * 32 + cr) << 9) + half * 256 + l31 * 8);
        u2 = *(const uint4*)(gpb + ((size_t)(g * 32 + cr + 16) << 9) + half * 256 + l31 * 8);
    };
    auto CONVROW = [&](const float* Wc, const uint4 gc, const uint4 b4, int row, char* tile) {
        const unsigned gw[4] = {gc.x, gc.y, gc.z, gc.w};
        const unsigned bw[4] = {b4.x, b4.y, b4.z, b4.w};
        float p[8];
        float s = 0.f, t2 = 0.f;
#pragma unroll
        for (int e = 0; e < 8; ++e) {
            unsigned ug = (e & 1) ? (gw[e >> 1] >> 16) : (gw[e >> 1] & 0xffffu);
            unsigned ub = (e & 1) ? (bw[e >> 1] >> 16) : (bw[e >> 1] & 0xffffu);
            p[e] = bfu((unsigned short)ug) * Wc[e];
            s += p[e];
            t2 = fmaf(bfu((unsigned short)ub), Wc[e], t2);
        }
        uint4 o4;
        o4.x = pkbf(p[0], p[1]); o4.y = pkbf(p[2], p[3]);
        o4.z = pkbf(p[4], p[5]); o4.w = pkbf(p[6], p[7]);
        *(uint4*)(tile + row * 512 + ((l31 * 16) ^ ((row & 15) << 4))) = o4;
        sg += s; sb += t2;
    };

    // prologue
    LOADW(0, 0, WrA); LOADG(0, 0, gaA1, gaA2);
    __syncthreads();   // B-fill visible (one-time vmcnt drain)

#pragma unroll 1
    for (int g = 0; g < 16; ++g) {
        // ================= half 0 =================
        uint4 bb1 = *(const uint4*)(bpb + ((size_t)(g * 32 + cr) << 9) + l31 * 8);
        uint4 bb2 = *(const uint4*)(bpb + ((size_t)(g * 32 + cr + 16) << 9) + l31 * 8);
        LOADW(g, 1, WrB); LOADG(g, 1, gaB1, gaB2);
        CONVROW(&WrA[0], gaA1, bb1, cr,      bt[0]);
        CONVROW(&WrA[8], gaA2, bb2, cr + 16, bt[0]);

        __builtin_amdgcn_sched_barrier(0);
        asm volatile("s_waitcnt lgkmcnt(0)" ::: "memory");
        __builtin_amdgcn_s_barrier();
        __builtin_amdgcn_sched_barrier(0);

#pragma unroll
        for (int i2 = 0; i2 < 8; ++i2) {
            int ksl = kslb + i2;
            s16x8 afr = *(const s16x8*)(&bt[0][l31 * 512 +
                          ((ksl * 32 + kg * 16) ^ ((l31 & 15) << 4))]);
            s16x8 bfr = *(const s16x8*)(&Bs[colm * 1024 +
                          ((ksl * 32 + kg * 16) ^ ((colm & 15) << 4))]);
            acc = __builtin_amdgcn_mfma_f32_32x32x16_bf16(afr, bfr, acc, 0, 0, 0);
        }

        // ================= half 1 =================
        uint4 cb1 = *(const uint4*)(bpb + ((size_t)(g * 32 + cr) << 9) + 256 + l31 * 8);
        uint4 cb2 = *(const uint4*)(bpb + ((size_t)(g * 32 + cr + 16) << 9) + 256 + l31 * 8);
        if (g < 15) { LOADW(g + 1, 0, WrA); LOADG(g + 1, 0, gaA1, gaA2); }
#pragma unroll
        for (int e = 0; e < 16; ++e) {
            int row32 = (e & 3) + 8 * (e >> 2) + 4 * kg;
            ahv[e] = ahT[(size_t)(g * 32 + row32) * 128 + colm];
        }
        CONVROW(&WrB[0], gaB1, cb1, cr,      bt[1]);
        CONVROW(&WrB[8], gaB2, cb2, cr + 16, bt[1]);

        __builtin_amdgcn_sched_barrier(0);
        asm volatile("s_waitcnt lgkmcnt(0)" ::: "memory");
        __builtin_amdgcn_s_barrier();
        __builtin_amdgcn_sched_barrier(0);

#pragma unroll
        for (int i2 = 0; i2 < 8; ++i2) {
            int ksl = kslb + i2;
            s16x8 afr = *(const s16x8*)(&bt[1][l31 * 512 +
                          ((ksl * 32 + kg * 16) ^ ((l31 & 15) << 4))]);
            s16x8 bfr = *(const s16x8*)(&Bs[colm * 1024 +
                          ((512 + ksl * 32 + kg * 16) ^ ((colm & 15) << 4))]);
            acc = __builtin_amdgcn_mfma_f32_32x32x16_bf16(afr, bfr, acc, 0, 0, 0);
        }
        // fold this group (C/D: col=lane&31, row=(e&3)+8*(e>>2)+4*(lane>>5))
#pragma unroll
        for (int e = 0; e < 16; ++e) psum = fmaf(acc[e], ahv[e], psum);
#pragma unroll
        for (int e = 0; e < 16; ++e) acc[e] = 0.f;
    }

    // ---- epilogue (reuse Bs as scratch after all reads done) ---------------
    __syncthreads();
    float* redP  = (float*)Bs;          // [128 cols][2 wave-pairs]
    float* redSg = redP + 256;
    float* redSb = redP + 264;
    psum += __shfl_xor(psum, 32);
#pragma unroll
    for (int off = 1; off < 64; off <<= 1) {
        sg += __shfl_xor(sg, off); sb += __shfl_xor(sb, off);
    }
    if (lane < 32) redP[colm * 2 + (w >> 2)] = psum;
    if (lane == 0) { redSg[w] = sg; redSb[w] = sb; }
    __syncthreads();
    if (tid < 128) Pout[(size_t)o * 128 + tid] = redP[tid * 2] + redP[tid * 2 + 1];
    if (tid == 0) {
        float S = 0.f, T = 0.f;
#pragma unroll
        for (int k = 0; k < 8; ++k) { S += redSg[k]; T += redSb[k]; }
        Sgo[o] = S; Sbo[o] = T;
    }
}

// ---------- finalize: i=512 row + j=512 col peels + LN fold + bias + relu ----
// 128 threads per block (m = threadIdx.x indexes the batch dim).
__global__ void finalize_kernel(const float* __restrict__ Pout, const float* __restrict__ Sgo,
                                const float* __restrict__ Sbo, const float* __restrict__ w5g,
                                const float* __restrict__ w5b, const float* __restrict__ ahT,
                                const float* __restrict__ vh512, const unsigned short* __restrict__ vhT,
                                const float* __restrict__ W, const float* __restrict__ gamma,
                                const float* __restrict__ beta, const float* __restrict__ mu,
                                const float* __restrict__ rsig, const float* __restrict__ bias,
                                float* __restrict__ out) {
    __shared__ float wg[HP], wb[HP], gws[512], bws[512];
    int o = blockIdx.x, m = threadIdx.x;   // 128 threads
    for (int i = m; i < HP; i += 128) {
        wg[i] = w5g[(size_t)o * HP + i];
        wb[i] = w5b[(size_t)o * HP + i];
    }
    // row i=512, j<512: gamma*W and beta*W in permuted slot order
    for (int j = m; j < 512; j += 128) {
        float wv = W[((size_t)o * 513u + 512u) * 513u + j];
        int s = ((j >> 8) << 8) + ((j & 31) << 3) + ((j & 255) >> 5);
        gws[s] = gamma[(size_t)512 * HP + j] * wv;
        bws[s] = beta [(size_t)512 * HP + j] * wv;
    }
    __syncthreads();
    float Pf = 0.f, Sgf = 0.f, Sbf = 0.f;
    for (int i = 0; i < HP; ++i) {
        float g = wg[i];
        Pf = fmaf(ahT[(size_t)i * 128 + m], g, Pf);
        Sgf += g; Sbf += wb[i];
    }
    float dot = 0.f, Sg2 = 0.f, Sb2 = 0.f;
    const unsigned short* vr = vhT + (size_t)m * 512;
    for (int s = 0; s < 512; ++s) {
        float g = gws[s];
        dot = fmaf(bfu(vr[s]), g, dot);
        Sg2 += g; Sb2 += bws[s];
    }
    float P  = Pout[(size_t)o * 128 + m] + vh512[m] * Pf + ahT[(size_t)512 * 128 + m] * dot;
    float Sg = Sgo[o] + Sgf + Sg2;
    float Sb = Sbo[o] + Sbf + Sb2;
    float x = rsig[m] * (P - mu[m] * Sg) + Sb + bias[o];
    out[m * OD + o] = fmaxf(x, 0.f);
}

extern "C" void kernel_launch(void* const* d_in, const int* in_sizes, int n_in,
                              void* d_out, int out_size, void* d_ws, size_t ws_size,
                              hipStream_t stream) {
    const float* a     = (const float*)d_in[0];
    const float* v     = (const float*)d_in[1];
    const float* gamma = (const float*)d_in[2];
    const float* beta  = (const float*)d_in[3];
    const float* W     = (const float*)d_in[4];
    const float* bias  = (const float*)d_in[5];
    float* out = (float*)d_out;

    float* cur = (float*)d_ws;
    float* mu    = cur; cur += 128;
    float* rsig  = cur; cur += 128;
    float* Sgo   = cur; cur += 256;
    float* Sbo   = cur; cur += 256;
    float* Pout  = cur; cur += (size_t)OD * 128;        // 32768
    float* ahT   = cur; cur += (size_t)HP * 128;        // 65664
    float* vh512 = cur; cur += 128;
    float* w5g   = cur; cur += (size_t)OD * HP;         // 131328
    float* w5b   = cur; cur += (size_t)OD * HP;         // 131328
    unsigned short* gpb = (unsigned short*)cur;          // 513*512
    unsigned short* bpb = gpb + (size_t)HP * 512;
    unsigned short* vhT = bpb + (size_t)HP * 512;        // 128*512

    prep_all<<<HP + 128 + 1 + 257, 256, 0, stream>>>(a, v, gamma, beta, gpb, bpb, vhT, vh512, ahT);
    prep_w5<<<HP, 256, 0, stream>>>(W, gamma, beta, w5g, w5b);
    stats_kernel<<<128, 256, 0, stream>>>(a, v, mu, rsig);
    stage_fused<<<OD, 512, 0, stream>>>(W, gpb, bpb, vhT, ahT, Pout, Sgo, Sbo);
    finalize_kernel<<<OD, 128, 0, stream>>>(Pout, Sgo, Sbo, w5g, w5b, ahT, vh512, vhT,
                                            W, gamma, beta, mu, rsig, bias, out);
}

// Round 18
// 99.418 us; speedup vs baseline: 1.4930x; 1.0642x over previous
//
#include <hip/hip_runtime.h>
#include <hip/hip_bf16.h>

#define HID 512
#define OD  256
#define HP  513
#define EPSV 1e-5f

typedef float f32x16 __attribute__((ext_vector_type(16)));
typedef short s16x8  __attribute__((ext_vector_type(8)));

static __device__ __forceinline__ unsigned short f2bf(float f) {
    union { float f; unsigned u; } x; x.f = f;
    unsigned r = x.u + 0x7FFFu + ((x.u >> 16) & 1u);   // RNE
    return (unsigned short)(r >> 16);
}
static __device__ __forceinline__ unsigned pkbf(float x, float y) {
    float2 t; t.x = x; t.y = y;
    __hip_bfloat162 h = __float22bfloat162_rn(t);
    union { __hip_bfloat162 h; unsigned u; } c; c.h = h;
    return c.u;
}
static __device__ __forceinline__ float bfu(unsigned short u) {
    union { unsigned q; float f; } cv; cv.q = ((unsigned)u) << 16;
    return cv.f;
}

// permuted k-storage: within a 256-col half, storage s=(ll*8+c) holds true col
// j = c*32+ll. Applied identically to gpb/bpb/vhT -> MFMA pairing consistent.

// ---------- prep (fused): gpb/bpb, vhT, vh512, ahT, stats --------------------
__global__ void prep_all(const float* __restrict__ a, const float* __restrict__ v,
                         const float* __restrict__ gamma, const float* __restrict__ beta,
                         unsigned short* __restrict__ gpb, unsigned short* __restrict__ bpb,
                         unsigned short* __restrict__ vhT, float* __restrict__ vh512,
                         float* __restrict__ ahT, float* __restrict__ mu,
                         float* __restrict__ rsig) {
    __shared__ float s1[256], s2[256], s3[256], s4[256];
    int b = blockIdx.x, t = threadIdx.x;
    if (b < HP) {
        int ii = b;
        for (int s = t; s < 512; s += 256) {
            int half = s >> 8, ss = s & 255, ll = ss >> 3, c = ss & 7;
            int j = half * 256 + c * 32 + ll;
            gpb[(size_t)ii * 512 + s] = f2bf(gamma[(size_t)ii * HP + j]);
            bpb[(size_t)ii * 512 + s] = f2bf(beta [(size_t)ii * HP + j]);
        }
    } else if (b < HP + 128) {
        int m = b - HP;
        for (int s = t; s < 512; s += 256) {
            int half = s >> 8, ss = s & 255, ll = ss >> 3, c = ss & 7;
            int j = half * 256 + c * 32 + ll;
            float val = (j == 0) ? 1.f : v[m * HID + j - 1];
            vhT[(size_t)m * 512 + s] = f2bf(val);
        }
    } else if (b == HP + 128) {
        if (t < 128) vh512[t] = v[t * HID + 511];
    } else if (b < HP + 129 + 257) {
        int idx = (b - HP - 129) * 256 + t;
        if (idx < HP * 128) {
            int i = idx >> 7, m = idx & 127;
            ahT[idx] = (i == 0) ? 1.f : a[m * HID + i - 1];
        }
    } else {
        int m = b - (HP + 129 + 257);
        float a0 = a[m * HID + t], a1 = a[m * HID + t + 256];
        float v0 = v[m * HID + t], v1 = v[m * HID + t + 256];
        s1[t] = a0 + a1; s2[t] = a0 * a0 + a1 * a1;
        s3[t] = v0 + v1; s4[t] = v0 * v0 + v1 * v1;
        __syncthreads();
        for (int off = 128; off > 0; off >>= 1) {
            if (t < off) { s1[t] += s1[t + off]; s2[t] += s2[t + off];
                           s3[t] += s3[t + off]; s4[t] += s4[t + off]; }
            __syncthreads();
        }
        if (t == 0) {
            float Sa = 1.f + s1[0], Qa = 1.f + s2[0];
            float Sv = 1.f + s3[0], Qv = 1.f + s4[0];
            float muv = Sa * Sv / (float)((float)HP * (float)HP);
            float var = Qa * Qv / (float)((float)HP * (float)HP) - muv * muv;
            mu[m]   = muv;
            rsig[m] = rsqrtf(var + EPSV);
        }
    }
}

// ---------- stage: block o owns rows o*513+i, i<512; 32x32x16 MFMA -----------
// Main loop BYTE-IDENTICAL to R13/R17 (measured 105.8). Added prologue-only
// w5 gather (this block's W col-512, scaled by gamma/beta -> w5g/w5b): loads
// issued before B-fill so scatter latency hides under the LDS fill; all
// values dead before the main loop starts.
__global__ __launch_bounds__(512, 2) void stage_fused(
        const float* __restrict__ W, const unsigned short* __restrict__ gpb,
        const unsigned short* __restrict__ bpb, const unsigned short* __restrict__ vhT,
        const float* __restrict__ ahT, const float* __restrict__ gamma,
        const float* __restrict__ beta, float* __restrict__ w5g, float* __restrict__ w5b,
        float* __restrict__ Pout, float* __restrict__ Sgo, float* __restrict__ Sbo) {
    __shared__ __align__(16) char Bs[131072];      // [128 cols][1024B], swz (m&15)<<4
    __shared__ __align__(16) char bt[2][16384];    // A dbuf: [32 rows][512B], swz (r&15)<<4

    const int tid = threadIdx.x, lane = tid & 63, w = tid >> 6;
    const int l31 = lane & 31, kg = lane >> 5;
    const int cr = 2 * w + kg;                 // conv row 0..15 (pairs with cr+16)
    const int colm = (w & 3) * 32 + l31;       // wave's output col
    const int kslb = (w >> 2) * 8;             // wave's ksl range
    const int o = blockIdx.x;
    const unsigned rbase = (unsigned)o * 513u;

    // ---- w5 gather: issue scattered loads FIRST (oldest in vmcnt queue) -----
    float w5w0 = W[(size_t)(rbase + (unsigned)tid) * 513u + 512u];
    float g50  = gamma[(size_t)tid * 513u + 512u];
    float b50  = beta [(size_t)tid * 513u + 512u];
    float w5w1 = 0.f, g51 = 0.f, b51 = 0.f;
    if (tid == 0) {
        w5w1 = W[(size_t)(rbase + 512u) * 513u + 512u];
        g51  = gamma[(size_t)512 * 513u + 512u];
        b51  = beta [(size_t)512 * 513u + 512u];
    }

    // ---- fill B (swizzled), chunked ----------------------------------------
#pragma unroll
    for (int q0 = 0; q0 < 16; q0 += 4) {
        uint4 vals[4];
#pragma unroll
        for (int qq = 0; qq < 4; ++qq) {
            int idx = tid + (q0 + qq) * 512;
            int mr = idx >> 6, c = idx & 63;
            vals[qq] = *(const uint4*)(vhT + (size_t)mr * 512 + c * 8);
        }
#pragma unroll
        for (int qq = 0; qq < 4; ++qq) {
            int idx = tid + (q0 + qq) * 512;
            int mr = idx >> 6, c = idx & 63;
            *(uint4*)(&Bs[mr * 1024 + ((c * 16) ^ ((mr & 15) << 4))]) = vals[qq];
        }
    }

    // ---- w5 consume + store (values dead afterwards) ------------------------
    w5g[(size_t)o * HP + tid] = g50 * w5w0;
    w5b[(size_t)o * HP + tid] = b50 * w5w0;
    if (tid == 0) {
        w5g[(size_t)o * HP + 512] = g51 * w5w1;
        w5b[(size_t)o * HP + 512] = b51 * w5w1;
    }

    float WrA[16], WrB[16];
    uint4 gaA1, gaA2, gaB1, gaB2;
    float ahv[16];
    f32x16 acc;
#pragma unroll
    for (int e = 0; e < 16; ++e) acc[e] = 0.f;
    float psum = 0.f, sg = 0.f, sb = 0.f;

    auto LOADW = [&](int g, int half, float (&dst)[16]) {
        const float* p1 = W + (size_t)(rbase + (unsigned)(g * 32 + cr)) * 513u + half * 256 + l31;
        const float* p2 = p1 + 16 * 513;
#pragma unroll
        for (int c = 0; c < 8; ++c) { dst[c] = p1[c * 32]; dst[8 + c] = p2[c * 32]; }
    };
    auto LOADG = [&](int g, int half, uint4& u1, uint4& u2) {
        u1 = *(const uint4*)(gpb + ((size_t)(g * 32 + cr) << 9) + half * 256 + l31 * 8);
        u2 = *(const uint4*)(gpb + ((size_t)(g * 32 + cr + 16) << 9) + half * 256 + l31 * 8);
    };
    auto CONVROW = [&](const float* Wc, const uint4 gc, const uint4 b4, int row, char* tile) {
        const unsigned gw[4] = {gc.x, gc.y, gc.z, gc.w};
        const unsigned bw[4] = {b4.x, b4.y, b4.z, b4.w};
        float p[8];
        float s = 0.f, t2 = 0.f;
#pragma unroll
        for (int e = 0; e < 8; ++e) {
            unsigned ug = (e & 1) ? (gw[e >> 1] >> 16) : (gw[e >> 1] & 0xffffu);
            unsigned ub = (e & 1) ? (bw[e >> 1] >> 16) : (bw[e >> 1] & 0xffffu);
            p[e] = bfu((unsigned short)ug) * Wc[e];
            s += p[e];
            t2 = fmaf(bfu((unsigned short)ub), Wc[e], t2);
        }
        uint4 o4;
        o4.x = pkbf(p[0], p[1]); o4.y = pkbf(p[2], p[3]);
        o4.z = pkbf(p[4], p[5]); o4.w = pkbf(p[6], p[7]);
        *(uint4*)(tile + row * 512 + ((l31 * 16) ^ ((row & 15) << 4))) = o4;
        sg += s; sb += t2;
    };

    // prologue
    LOADW(0, 0, WrA); LOADG(0, 0, gaA1, gaA2);
    __syncthreads();   // B-fill visible (one-time vmcnt drain)

#pragma unroll 1
    for (int g = 0; g < 16; ++g) {
        // ================= half 0 =================
        uint4 bb1 = *(const uint4*)(bpb + ((size_t)(g * 32 + cr) << 9) + l31 * 8);
        uint4 bb2 = *(const uint4*)(bpb + ((size_t)(g * 32 + cr + 16) << 9) + l31 * 8);
        LOADW(g, 1, WrB); LOADG(g, 1, gaB1, gaB2);
        CONVROW(&WrA[0], gaA1, bb1, cr,      bt[0]);
        CONVROW(&WrA[8], gaA2, bb2, cr + 16, bt[0]);

        __builtin_amdgcn_sched_barrier(0);
        asm volatile("s_waitcnt lgkmcnt(0)" ::: "memory");
        __builtin_amdgcn_s_barrier();
        __builtin_amdgcn_sched_barrier(0);

#pragma unroll
        for (int i2 = 0; i2 < 8; ++i2) {
            int ksl = kslb + i2;
            s16x8 afr = *(const s16x8*)(&bt[0][l31 * 512 +
                          ((ksl * 32 + kg * 16) ^ ((l31 & 15) << 4))]);
            s16x8 bfr = *(const s16x8*)(&Bs[colm * 1024 +
                          ((ksl * 32 + kg * 16) ^ ((colm & 15) << 4))]);
            acc = __builtin_amdgcn_mfma_f32_32x32x16_bf16(afr, bfr, acc, 0, 0, 0);
        }

        // ================= half 1 =================
        uint4 cb1 = *(const uint4*)(bpb + ((size_t)(g * 32 + cr) << 9) + 256 + l31 * 8);
        uint4 cb2 = *(const uint4*)(bpb + ((size_t)(g * 32 + cr + 16) << 9) + 256 + l31 * 8);
        if (g < 15) { LOADW(g + 1, 0, WrA); LOADG(g + 1, 0, gaA1, gaA2); }
#pragma unroll
        for (int e = 0; e < 16; ++e) {
            int row32 = (e & 3) + 8 * (e >> 2) + 4 * kg;
            ahv[e] = ahT[(size_t)(g * 32 + row32) * 128 + colm];
        }
        CONVROW(&WrB[0], gaB1, cb1, cr,      bt[1]);
        CONVROW(&WrB[8], gaB2, cb2, cr + 16, bt[1]);

        __builtin_amdgcn_sched_barrier(0);
        asm volatile("s_waitcnt lgkmcnt(0)" ::: "memory");
        __builtin_amdgcn_s_barrier();
        __builtin_amdgcn_sched_barrier(0);

#pragma unroll
        for (int i2 = 0; i2 < 8; ++i2) {
            int ksl = kslb + i2;
            s16x8 afr = *(const s16x8*)(&bt[1][l31 * 512 +
                          ((ksl * 32 + kg * 16) ^ ((l31 & 15) << 4))]);
            s16x8 bfr = *(const s16x8*)(&Bs[colm * 1024 +
                          ((512 + ksl * 32 + kg * 16) ^ ((colm & 15) << 4))]);
            acc = __builtin_amdgcn_mfma_f32_32x32x16_bf16(afr, bfr, acc, 0, 0, 0);
        }
        // fold this group (C/D: col=lane&31, row=(e&3)+8*(e>>2)+4*(lane>>5))
#pragma unroll
        for (int e = 0; e < 16; ++e) psum = fmaf(acc[e], ahv[e], psum);
#pragma unroll
        for (int e = 0; e < 16; ++e) acc[e] = 0.f;
    }

    // ---- epilogue (reuse Bs as scratch after all reads done) ---------------
    __syncthreads();
    float* redP  = (float*)Bs;          // [128 cols][2 wave-pairs]
    float* redSg = redP + 256;
    float* redSb = redP + 264;
    psum += __shfl_xor(psum, 32);
#pragma unroll
    for (int off = 1; off < 64; off <<= 1) {
        sg += __shfl_xor(sg, off); sb += __shfl_xor(sb, off);
    }
    if (lane < 32) redP[colm * 2 + (w >> 2)] = psum;
    if (lane == 0) { redSg[w] = sg; redSb[w] = sb; }
    __syncthreads();
    if (tid < 128) Pout[(size_t)o * 128 + tid] = redP[tid * 2] + redP[tid * 2 + 1];
    if (tid == 0) {
        float S = 0.f, T = 0.f;
#pragma unroll
        for (int k = 0; k < 8; ++k) { S += redSg[k]; T += redSb[k]; }
        Sgo[o] = S; Sbo[o] = T;
    }
}

// ---------- finalize: i=512 row + j=512 col peels + LN fold + bias + relu ----
// 128 threads per block (m = threadIdx.x indexes the batch dim). R13 version.
__global__ void finalize_kernel(const float* __restrict__ Pout, const float* __restrict__ Sgo,
                                const float* __restrict__ Sbo, const float* __restrict__ w5g,
                                const float* __restrict__ w5b, const float* __restrict__ ahT,
                                const float* __restrict__ vh512, const unsigned short* __restrict__ vhT,
                                const float* __restrict__ W, const float* __restrict__ gamma,
                                const float* __restrict__ beta, const float* __restrict__ mu,
                                const float* __restrict__ rsig, const float* __restrict__ bias,
                                float* __restrict__ out) {
    __shared__ float wg[HP], wb[HP], gws[512], bws[512];
    int o = blockIdx.x, m = threadIdx.x;   // 128 threads
    for (int i = m; i < HP; i += 128) {
        wg[i] = w5g[(size_t)o * HP + i];
        wb[i] = w5b[(size_t)o * HP + i];
    }
    // row i=512, j<512: gamma*W and beta*W in permuted slot order
    for (int j = m; j < 512; j += 128) {
        float wv = W[((size_t)o * 513u + 512u) * 513u + j];
        int s = ((j >> 8) << 8) + ((j & 31) << 3) + ((j & 255) >> 5);
        gws[s] = gamma[(size_t)512 * HP + j] * wv;
        bws[s] = beta [(size_t)512 * HP + j] * wv;
    }
    __syncthreads();
    float Pf = 0.f, Sgf = 0.f, Sbf = 0.f;
    for (int i = 0; i < HP; ++i) {
        float g = wg[i];
        Pf = fmaf(ahT[(size_t)i * 128 + m], g, Pf);
        Sgf += g; Sbf += wb[i];
    }
    float dot = 0.f, Sg2 = 0.f, Sb2 = 0.f;
    const unsigned short* vr = vhT + (size_t)m * 512;
    for (int s = 0; s < 512; ++s) {
        float g = gws[s];
        dot = fmaf(bfu(vr[s]), g, dot);
        Sg2 += g; Sb2 += bws[s];
    }
    float P  = Pout[(size_t)o * 128 + m] + vh512[m] * Pf + ahT[(size_t)512 * 128 + m] * dot;
    float Sg = Sgo[o] + Sgf + Sg2;
    float Sb = Sbo[o] + Sbf + Sb2;
    float x = rsig[m] * (P - mu[m] * Sg) + Sb + bias[o];
    out[m * OD + o] = fmaxf(x, 0.f);
}

extern "C" void kernel_launch(void* const* d_in, const int* in_sizes, int n_in,
                              void* d_out, int out_size, void* d_ws, size_t ws_size,
                              hipStream_t stream) {
    const float* a     = (const float*)d_in[0];
    const float* v     = (const float*)d_in[1];
    const float* gamma = (const float*)d_in[2];
    const float* beta  = (const float*)d_in[3];
    const float* W     = (const float*)d_in[4];
    const float* bias  = (const float*)d_in[5];
    float* out = (float*)d_out;

    float* cur = (float*)d_ws;
    float* mu    = cur; cur += 128;
    float* rsig  = cur; cur += 128;
    float* Sgo   = cur; cur += 256;
    float* Sbo   = cur; cur += 256;
    float* Pout  = cur; cur += (size_t)OD * 128;        // 32768
    float* ahT   = cur; cur += (size_t)HP * 128;        // 65664
    float* vh512 = cur; cur += 128;
    float* w5g   = cur; cur += (size_t)OD * HP;         // 131328
    float* w5b   = cur; cur += (size_t)OD * HP;         // 131328
    unsigned short* gpb = (unsigned short*)cur;          // 513*512
    unsigned short* bpb = gpb + (size_t)HP * 512;
    unsigned short* vhT = bpb + (size_t)HP * 512;        // 128*512

    prep_all<<<HP + 129 + 257 + 128, 256, 0, stream>>>(a, v, gamma, beta, gpb, bpb,
                                                       vhT, vh512, ahT, mu, rsig);
    stage_fused<<<OD, 512, 0, stream>>>(W, gpb, bpb, vhT, ahT, gamma, beta, w5g, w5b,
                                        Pout, Sgo, Sbo);
    finalize_kernel<<<OD, 128, 0, stream>>>(Pout, Sgo, Sbo, w5g, w5b, ahT, vh512, vhT,
                                            W, gamma, beta, mu, rsig, bias, out);
}

// Round 19
// 87.337 us; speedup vs baseline: 1.6995x; 1.1383x over previous
//
#include <hip/hip_runtime.h>
#include <hip/hip_bf16.h>

#define HID 512
#define OD  256
#define HP  513
#define EPSV 1e-5f

typedef float f32x16 __attribute__((ext_vector_type(16)));
typedef short s16x8  __attribute__((ext_vector_type(8)));

static __device__ __forceinline__ unsigned short f2bf(float f) {
    union { float f; unsigned u; } x; x.f = f;
    unsigned r = x.u + 0x7FFFu + ((x.u >> 16) & 1u);   // RNE
    return (unsigned short)(r >> 16);
}
static __device__ __forceinline__ unsigned pkbf(float x, float y) {
    float2 t; t.x = x; t.y = y;
    __hip_bfloat162 h = __float22bfloat162_rn(t);
    union { __hip_bfloat162 h; unsigned u; } c; c.h = h;
    return c.u;
}
static __device__ __forceinline__ float bfu(unsigned short u) {
    union { unsigned q; float f; } cv; cv.q = ((unsigned)u) << 16;
    return cv.f;
}

// permuted k-storage: within a 256-col half, storage s=(ll*8+c) holds true col
// j = c*32+ll. Applied identically to gpb/bpb/vhT -> MFMA pairing consistent.

// ---------- prep (fused): gpb/bpb, vhT, vh512, ahT, stats --------------------
__global__ void prep_all(const float* __restrict__ a, const float* __restrict__ v,
                         const float* __restrict__ gamma, const float* __restrict__ beta,
                         unsigned short* __restrict__ gpb, unsigned short* __restrict__ bpb,
                         unsigned short* __restrict__ vhT, float* __restrict__ vh512,
                         float* __restrict__ ahT, float* __restrict__ mu,
                         float* __restrict__ rsig) {
    __shared__ float s1[256], s2[256], s3[256], s4[256];
    int b = blockIdx.x, t = threadIdx.x;
    if (b < HP) {
        int ii = b;
        for (int s = t; s < 512; s += 256) {
            int half = s >> 8, ss = s & 255, ll = ss >> 3, c = ss & 7;
            int j = half * 256 + c * 32 + ll;
            gpb[(size_t)ii * 512 + s] = f2bf(gamma[(size_t)ii * HP + j]);
            bpb[(size_t)ii * 512 + s] = f2bf(beta [(size_t)ii * HP + j]);
        }
    } else if (b < HP + 128) {
        int m = b - HP;
        for (int s = t; s < 512; s += 256) {
            int half = s >> 8, ss = s & 255, ll = ss >> 3, c = ss & 7;
            int j = half * 256 + c * 32 + ll;
            float val = (j == 0) ? 1.f : v[m * HID + j - 1];
            vhT[(size_t)m * 512 + s] = f2bf(val);
        }
    } else if (b == HP + 128) {
        if (t < 128) vh512[t] = v[t * HID + 511];
    } else if (b < HP + 129 + 257) {
        int idx = (b - HP - 129) * 256 + t;
        if (idx < HP * 128) {
            int i = idx >> 7, m = idx & 127;
            ahT[idx] = (i == 0) ? 1.f : a[m * HID + i - 1];
        }
    } else {
        int m = b - (HP + 129 + 257);
        float a0 = a[m * HID + t], a1 = a[m * HID + t + 256];
        float v0 = v[m * HID + t], v1 = v[m * HID + t + 256];
        s1[t] = a0 + a1; s2[t] = a0 * a0 + a1 * a1;
        s3[t] = v0 + v1; s4[t] = v0 * v0 + v1 * v1;
        __syncthreads();
        for (int off = 128; off > 0; off >>= 1) {
            if (t < off) { s1[t] += s1[t + off]; s2[t] += s2[t + off];
                           s3[t] += s3[t + off]; s4[t] += s4[t + off]; }
            __syncthreads();
        }
        if (t == 0) {
            float Sa = 1.f + s1[0], Qa = 1.f + s2[0];
            float Sv = 1.f + s3[0], Qv = 1.f + s4[0];
            float muv = Sa * Sv / (float)((float)HP * (float)HP);
            float var = Qa * Qv / (float)((float)HP * (float)HP) - muv * muv;
            mu[m]   = muv;
            rsig[m] = rsqrtf(var + EPSV);
        }
    }
}

// ---------- stage: block o owns rows o*513+i, i<512; 32x32x16 MFMA -----------
// Main loop BYTE-IDENTICAL to R13/R17/R18. Prologue: w5 gather (as R18).
// Epilogue: full finalize fused in (reductions in bt; Bs keeps vhT for the
// i=512-row dot); writes out[] directly. No finalize launch.
__global__ __launch_bounds__(512, 2) void stage_fused(
        const float* __restrict__ W, const unsigned short* __restrict__ gpb,
        const unsigned short* __restrict__ bpb, const unsigned short* __restrict__ vhT,
        const float* __restrict__ ahT, const float* __restrict__ gamma,
        const float* __restrict__ beta, float* __restrict__ w5g, float* __restrict__ w5b,
        const float* __restrict__ vh512, const float* __restrict__ mu,
        const float* __restrict__ rsig, const float* __restrict__ bias,
        float* __restrict__ out) {
    __shared__ __align__(16) char Bs[131072];      // [128 cols][1024B], swz (m&15)<<4
    __shared__ __align__(16) char bt[2][16384];    // A dbuf: [32 rows][512B], swz (r&15)<<4

    const int tid = threadIdx.x, lane = tid & 63, w = tid >> 6;
    const int l31 = lane & 31, kg = lane >> 5;
    const int cr = 2 * w + kg;                 // conv row 0..15 (pairs with cr+16)
    const int colm = (w & 3) * 32 + l31;       // wave's output col
    const int kslb = (w >> 2) * 8;             // wave's ksl range
    const int o = blockIdx.x;
    const unsigned rbase = (unsigned)o * 513u;

    // ---- w5 gather: issue scattered loads FIRST (oldest in vmcnt queue) -----
    float w5w0 = W[(size_t)(rbase + (unsigned)tid) * 513u + 512u];
    float g50  = gamma[(size_t)tid * 513u + 512u];
    float b50  = beta [(size_t)tid * 513u + 512u];
    float w5w1 = 0.f, g51 = 0.f, b51 = 0.f;
    if (tid == 0) {
        w5w1 = W[(size_t)(rbase + 512u) * 513u + 512u];
        g51  = gamma[(size_t)512 * 513u + 512u];
        b51  = beta [(size_t)512 * 513u + 512u];
    }

    // ---- fill B (swizzled), chunked ----------------------------------------
#pragma unroll
    for (int q0 = 0; q0 < 16; q0 += 4) {
        uint4 vals[4];
#pragma unroll
        for (int qq = 0; qq < 4; ++qq) {
            int idx = tid + (q0 + qq) * 512;
            int mr = idx >> 6, c = idx & 63;
            vals[qq] = *(const uint4*)(vhT + (size_t)mr * 512 + c * 8);
        }
#pragma unroll
        for (int qq = 0; qq < 4; ++qq) {
            int idx = tid + (q0 + qq) * 512;
            int mr = idx >> 6, c = idx & 63;
            *(uint4*)(&Bs[mr * 1024 + ((c * 16) ^ ((mr & 15) << 4))]) = vals[qq];
        }
    }

    // ---- w5 consume + store (values dead afterwards; re-read in epilogue) --
    w5g[(size_t)o * HP + tid] = g50 * w5w0;
    w5b[(size_t)o * HP + tid] = b50 * w5w0;
    if (tid == 0) {
        w5g[(size_t)o * HP + 512] = g51 * w5w1;
        w5b[(size_t)o * HP + 512] = b51 * w5w1;
    }

    float WrA[16], WrB[16];
    uint4 gaA1, gaA2, gaB1, gaB2;
    float ahv[16];
    f32x16 acc;
#pragma unroll
    for (int e = 0; e < 16; ++e) acc[e] = 0.f;
    float psum = 0.f, sg = 0.f, sb = 0.f;

    auto LOADW = [&](int g, int half, float (&dst)[16]) {
        const float* p1 = W + (size_t)(rbase + (unsigned)(g * 32 + cr)) * 513u + half * 256 + l31;
        const float* p2 = p1 + 16 * 513;
#pragma unroll
        for (int c = 0; c < 8; ++c) { dst[c] = p1[c * 32]; dst[8 + c] = p2[c * 32]; }
    };
    auto LOADG = [&](int g, int half, uint4& u1, uint4& u2) {
        u1 = *(const uint4*)(gpb + ((size_t)(g * 32 + cr) << 9) + half * 256 + l31 * 8);
        u2 = *(const uint4*)(gpb + ((size_t)(g * 32 + cr + 16) << 9) + half * 256 + l31 * 8);
    };
    auto CONVROW = [&](const float* Wc, const uint4 gc, const uint4 b4, int row, char* tile) {
        const unsigned gw[4] = {gc.x, gc.y, gc.z, gc.w};
        const unsigned bw[4] = {b4.x, b4.y, b4.z, b4.w};
        float p[8];
        float s = 0.f, t2 = 0.f;
#pragma unroll
        for (int e = 0; e < 8; ++e) {
            unsigned ug = (e & 1) ? (gw[e >> 1] >> 16) : (gw[e >> 1] & 0xffffu);
            unsigned ub = (e & 1) ? (bw[e >> 1] >> 16) : (bw[e >> 1] & 0xffffu);
            p[e] = bfu((unsigned short)ug) * Wc[e];
            s += p[e];
            t2 = fmaf(bfu((unsigned short)ub), Wc[e], t2);
        }
        uint4 o4;
        o4.x = pkbf(p[0], p[1]); o4.y = pkbf(p[2], p[3]);
        o4.z = pkbf(p[4], p[5]); o4.w = pkbf(p[6], p[7]);
        *(uint4*)(tile + row * 512 + ((l31 * 16) ^ ((row & 15) << 4))) = o4;
        sg += s; sb += t2;
    };

    // prologue
    LOADW(0, 0, WrA); LOADG(0, 0, gaA1, gaA2);
    __syncthreads();   // B-fill visible (one-time vmcnt drain)

#pragma unroll 1
    for (int g = 0; g < 16; ++g) {
        // ================= half 0 =================
        uint4 bb1 = *(const uint4*)(bpb + ((size_t)(g * 32 + cr) << 9) + l31 * 8);
        uint4 bb2 = *(const uint4*)(bpb + ((size_t)(g * 32 + cr + 16) << 9) + l31 * 8);
        LOADW(g, 1, WrB); LOADG(g, 1, gaB1, gaB2);
        CONVROW(&WrA[0], gaA1, bb1, cr,      bt[0]);
        CONVROW(&WrA[8], gaA2, bb2, cr + 16, bt[0]);

        __builtin_amdgcn_sched_barrier(0);
        asm volatile("s_waitcnt lgkmcnt(0)" ::: "memory");
        __builtin_amdgcn_s_barrier();
        __builtin_amdgcn_sched_barrier(0);

#pragma unroll
        for (int i2 = 0; i2 < 8; ++i2) {
            int ksl = kslb + i2;
            s16x8 afr = *(const s16x8*)(&bt[0][l31 * 512 +
                          ((ksl * 32 + kg * 16) ^ ((l31 & 15) << 4))]);
            s16x8 bfr = *(const s16x8*)(&Bs[colm * 1024 +
                          ((ksl * 32 + kg * 16) ^ ((colm & 15) << 4))]);
            acc = __builtin_amdgcn_mfma_f32_32x32x16_bf16(afr, bfr, acc, 0, 0, 0);
        }

        // ================= half 1 =================
        uint4 cb1 = *(const uint4*)(bpb + ((size_t)(g * 32 + cr) << 9) + 256 + l31 * 8);
        uint4 cb2 = *(const uint4*)(bpb + ((size_t)(g * 32 + cr + 16) << 9) + 256 + l31 * 8);
        if (g < 15) { LOADW(g + 1, 0, WrA); LOADG(g + 1, 0, gaA1, gaA2); }
#pragma unroll
        for (int e = 0; e < 16; ++e) {
            int row32 = (e & 3) + 8 * (e >> 2) + 4 * kg;
            ahv[e] = ahT[(size_t)(g * 32 + row32) * 128 + colm];
        }
        CONVROW(&WrB[0], gaB1, cb1, cr,      bt[1]);
        CONVROW(&WrB[8], gaB2, cb2, cr + 16, bt[1]);

        __builtin_amdgcn_sched_barrier(0);
        asm volatile("s_waitcnt lgkmcnt(0)" ::: "memory");
        __builtin_amdgcn_s_barrier();
        __builtin_amdgcn_sched_barrier(0);

#pragma unroll
        for (int i2 = 0; i2 < 8; ++i2) {
            int ksl = kslb + i2;
            s16x8 afr = *(const s16x8*)(&bt[1][l31 * 512 +
                          ((ksl * 32 + kg * 16) ^ ((l31 & 15) << 4))]);
            s16x8 bfr = *(const s16x8*)(&Bs[colm * 1024 +
                          ((512 + ksl * 32 + kg * 16) ^ ((colm & 15) << 4))]);
            acc = __builtin_amdgcn_mfma_f32_32x32x16_bf16(afr, bfr, acc, 0, 0, 0);
        }
        // fold this group (C/D: col=lane&31, row=(e&3)+8*(e>>2)+4*(lane>>5))
#pragma unroll
        for (int e = 0; e < 16; ++e) psum = fmaf(acc[e], ahv[e], psum);
#pragma unroll
        for (int e = 0; e < 16; ++e) acc[e] = 0.f;
    }

    // ---- fused epilogue + finalize (bt reused; Bs keeps vhT for the dot) ----
    __syncthreads();
    float* redP  = (float*)bt;              // [128][2]
    float* redSg = redP + 256;              // [8]
    float* redSb = redP + 264;              // [8]
    float* bcST  = redP + 272;              // [2]
    float* wgL   = redP + 288;              // [513]
    float* wbL   = wgL + 520;               // [513]
    float* gwsL  = wbL + 520;               // [512] (permuted slots)
    float* bwsL  = gwsL + 512;              // [512]
    float* PfP   = bwsL + 512;              // [4][128]
    float* dotP  = PfP + 512;               // [4][128]
    float* sgP   = dotP + 512;              // [4]
    float* sbP   = sgP + 4;                 // [4]

    psum += __shfl_xor(psum, 32);
#pragma unroll
    for (int off = 1; off < 64; off <<= 1) {
        sg += __shfl_xor(sg, off); sb += __shfl_xor(sb, off);
    }
    if (lane < 32) redP[colm * 2 + (w >> 2)] = psum;
    if (lane == 0) { redSg[w] = sg; redSb[w] = sb; }
    // load finalize vectors: wg/wb (own writes, L2-hot) + row i=512 of W
    {
        wgL[tid] = w5g[(size_t)o * HP + tid];
        wbL[tid] = w5b[(size_t)o * HP + tid];
        if (tid == 0) {
            wgL[512] = w5g[(size_t)o * HP + 512];
            wbL[512] = w5b[(size_t)o * HP + 512];
        }
        float wv = W[(size_t)(rbase + 512u) * 513u + (unsigned)tid];
        int s = ((tid >> 8) << 8) + ((tid & 31) << 3) + ((tid & 255) >> 5);
        gwsL[s] = gamma[(size_t)512 * HP + tid] * wv;
        bwsL[s] = beta [(size_t)512 * HP + tid] * wv;
    }
    __syncthreads();
    if (tid == 0) {
        float S = 0.f, T = 0.f;
#pragma unroll
        for (int k = 0; k < 8; ++k) { S += redSg[k]; T += redSb[k]; }
        bcST[0] = S; bcST[1] = T;
    }
    // 4-way-split folds: h = group, m2 = batch index
    {
        const int h = tid >> 7, m2 = tid & 127;
        float Pf = 0.f, dt = 0.f, sgf = 0.f, sbf = 0.f;
        for (int i = h; i < 513; i += 4) {
            float g = wgL[i];
            Pf = fmaf(ahT[(size_t)i * 128 + m2], g, Pf);
            sgf += g; sbf += wbL[i];
        }
        for (int c = h; c < 64; c += 4) {
            s16x8 vv = *(const s16x8*)(&Bs[m2 * 1024 + ((c * 16) ^ ((m2 & 15) << 4))]);
            const float* gp  = gwsL + c * 8;
            const float* bp2 = bwsL + c * 8;
#pragma unroll
            for (int e = 0; e < 8; ++e) {
                dt = fmaf(bfu((unsigned short)vv[e]), gp[e], dt);
                sgf += gp[e]; sbf += bp2[e];
            }
        }
        PfP[h * 128 + m2] = Pf; dotP[h * 128 + m2] = dt;
        if (m2 == 0) { sgP[h] = sgf; sbP[h] = sbf; }
    }
    __syncthreads();
    if (tid < 128) {
        int m = tid;
        float Pb  = redP[m * 2] + redP[m * 2 + 1];
        float Pft = PfP[m] + PfP[128 + m] + PfP[256 + m] + PfP[384 + m];
        float dtt = dotP[m] + dotP[128 + m] + dotP[256 + m] + dotP[384 + m];
        float Sg  = bcST[0] + sgP[0] + sgP[1] + sgP[2] + sgP[3];
        float Sb  = bcST[1] + sbP[0] + sbP[1] + sbP[2] + sbP[3];
        float P   = Pb + vh512[m] * Pft + ahT[(size_t)512 * 128 + m] * dtt;
        float x   = rsig[m] * (P - mu[m] * Sg) + Sb + bias[o];
        out[m * OD + o] = fmaxf(x, 0.f);
    }
}

extern "C" void kernel_launch(void* const* d_in, const int* in_sizes, int n_in,
                              void* d_out, int out_size, void* d_ws, size_t ws_size,
                              hipStream_t stream) {
    const float* a     = (const float*)d_in[0];
    const float* v     = (const float*)d_in[1];
    const float* gamma = (const float*)d_in[2];
    const float* beta  = (const float*)d_in[3];
    const float* W     = (const float*)d_in[4];
    const float* bias  = (const float*)d_in[5];
    float* out = (float*)d_out;

    float* cur = (float*)d_ws;
    float* mu    = cur; cur += 128;
    float* rsig  = cur; cur += 128;
    float* ahT   = cur; cur += (size_t)HP * 128;        // 65664
    float* vh512 = cur; cur += 128;
    float* w5g   = cur; cur += (size_t)OD * HP;         // 131328
    float* w5b   = cur; cur += (size_t)OD * HP;         // 131328
    unsigned short* gpb = (unsigned short*)cur;          // 513*512
    unsigned short* bpb = gpb + (size_t)HP * 512;
    unsigned short* vhT = bpb + (size_t)HP * 512;        // 128*512

    prep_all<<<HP + 129 + 257 + 128, 256, 0, stream>>>(a, v, gamma, beta, gpb, bpb,
                                                       vhT, vh512, ahT, mu, rsig);
    stage_fused<<<OD, 512, 0, stream>>>(W, gpb, bpb, vhT, ahT, gamma, beta, w5g, w5b,
                                        vh512, mu, rsig, bias, out);
}